// Round 7
// baseline (2548.648 us; speedup 1.0000x reference)
//
#include <hip/hip_runtime.h>
#include <hip/hip_cooperative_groups.h>

namespace cg = cooperative_groups;

#define HID 128
#define TWO_HID 256
#define NEMB (HID*HID)
#define NWS  (4*HID*TWO_HID)

typedef __attribute__((ext_vector_type(8))) short short8;
typedef __attribute__((ext_vector_type(4))) float f32x4;

__device__ inline unsigned short f2b(float f){
  unsigned u = __float_as_uint(f);
  unsigned r = u + 0x7FFFu + ((u >> 16) & 1u);   // RNE
  return (unsigned short)(r >> 16);
}
__device__ inline unsigned pack2(float lo, float hi){
  return (unsigned)f2b(lo) | ((unsigned)f2b(hi) << 16);
}
__device__ inline float blo(unsigned u){ return __uint_as_float(u << 16); }
__device__ inline float bhi(unsigned u){ return __uint_as_float(u & 0xFFFF0000u); }

struct MegaParams {
  const float* h0; const int* src; const int* dst;
  const float* Wemb; const float* bemb; const float* Ws; const float* bs;
  const float* gam; const float* bet;
  float* h;
  int* deg; int* cursor; float* colsums; int* offs; int* loc; int* bsum;
  float* invd; int* ssrc;
  unsigned short* Wembb; unsigned short* Wsb;
  unsigned short* xh; unsigned short* cbt; float* zb;
  int N, E, Ntiles, NB;
};

// ================= single cooperative mega-kernel =================
__global__ __launch_bounds__(256, 4) void k_mega(MegaParams p){
  cg::grid_group gg = cg::this_grid();
  __shared__ int wsum[4];
  __shared__ float rowss[2][16][4];

  const int tid  = threadIdx.x;
  const int gsz  = gridDim.x * 256;
  const int gid0 = blockIdx.x * 256 + tid;
  const int w = tid >> 6, l = tid & 63;
  const int l15 = l & 15, lhi = l >> 4;
  const int ccol = w * 32;

  // ---- ph0: weight f32->bf16 (deg/cursor/colsums zeroed by host memset node) ----
  for (int i = gid0; i < NEMB + NWS; i += gsz){
    if (i < NEMB) p.Wembb[i] = f2b(p.Wemb[i]);
    else          p.Wsb[i - NEMB] = f2b(p.Ws[i - NEMB]);
  }
  gg.sync();

  // ---- ph1: degree count ----
  for (int e = gid0; e < p.E; e += gsz) atomicAdd(&p.deg[p.dst[e]], 1);
  gg.sync();

  // ---- ph2: scan pass 1 (per-256-chunk scan + chunk sums) ----
  for (int c = blockIdx.x; c < p.NB; c += gridDim.x){
    const int i = c*256 + tid;
    int v = (i < p.N) ? p.deg[i] : 0;
    int s = v;
    #pragma unroll
    for (int m=1; m<64; m<<=1){
      int t = __shfl_up(s, m, 64);
      if (l >= m) s += t;
    }
    if (l == 63) wsum[w] = s;
    __syncthreads();
    if (tid == 0){
      int a = 0;
      #pragma unroll
      for (int q=0;q<4;q++){ int t = wsum[q]; wsum[q] = a; a += t; }
      p.bsum[c] = a;
    }
    __syncthreads();
    if (i < p.N) p.loc[i] = s - v + wsum[w];
    __syncthreads();
  }
  gg.sync();

  // ---- ph3: scan pass 2 (chunk sums, NB<=256, block 0) ----
  if (blockIdx.x == 0){
    int v = (tid < p.NB) ? p.bsum[tid] : 0;
    int s = v;
    #pragma unroll
    for (int m=1; m<64; m<<=1){
      int t = __shfl_up(s, m, 64);
      if (l >= m) s += t;
    }
    if (l == 63) wsum[w] = s;
    __syncthreads();
    if (tid == 0){
      int a = 0;
      #pragma unroll
      for (int q=0;q<4;q++){ int t = wsum[q]; wsum[q] = a; a += t; }
    }
    __syncthreads();
    if (tid < p.NB) p.bsum[tid] = s - v + wsum[w];
  }
  gg.sync();

  // ---- ph4: offs = loc + bsum[chunk]; invd ----
  for (int i = gid0; i < p.N; i += gsz){
    p.offs[i] = p.loc[i] + p.bsum[i >> 8];
    int d = p.deg[i];
    p.invd[i] = 1.0f / (float)(d>1?d:1);
  }
  if (gid0 == 0) p.offs[p.N] = p.E;
  gg.sync();

  // ---- ph5: counting-sort fill ----
  for (int e = gid0; e < p.E; e += gsz){
    int d = p.dst[e];
    int pos = p.offs[d] + atomicAdd(&p.cursor[d], 1);
    p.ssrc[pos] = p.src[e];
  }
  gg.sync();

  // ---- ph6: input embedding (MFMA bf16): h = h0 @ Wemb^T + bemb ----
  {
    short8 bfr[2][4];
    #pragma unroll
    for (int t=0;t<2;t++){
      #pragma unroll
      for (int s=0;s<4;s++)
        bfr[t][s] = *(const short8*)(p.Wembb + (size_t)(ccol + t*16 + l15)*HID + s*32 + lhi*8);
    }
    const float bias0 = p.bemb[ccol + l15];
    const float bias1 = p.bemb[ccol + 16 + l15];
    for (int tile = blockIdx.x; tile < p.Ntiles; tile += gridDim.x){
      const int row0 = tile * 16;
      f32x4 acc0 = {0.f,0.f,0.f,0.f}, acc1 = {0.f,0.f,0.f,0.f};
      #pragma unroll
      for (int s=0;s<4;s++){
        const float* ap = p.h0 + (size_t)(row0 + l15)*HID + s*32 + lhi*8;
        float4 x0 = *(const float4*)ap;
        float4 x1 = *(const float4*)(ap + 4);
        short8 f;
        f[0]=(short)f2b(x0.x); f[1]=(short)f2b(x0.y); f[2]=(short)f2b(x0.z); f[3]=(short)f2b(x0.w);
        f[4]=(short)f2b(x1.x); f[5]=(short)f2b(x1.y); f[6]=(short)f2b(x1.z); f[7]=(short)f2b(x1.w);
        acc0 = __builtin_amdgcn_mfma_f32_16x16x32_bf16(f, bfr[0][s], acc0, 0,0,0);
        acc1 = __builtin_amdgcn_mfma_f32_16x16x32_bf16(f, bfr[1][s], acc1, 0,0,0);
      }
      #pragma unroll
      for (int r=0;r<4;r++){
        const int row = row0 + lhi*4 + r;
        float v0 = acc0[r] + bias0;
        float v1 = acc1[r] + bias1;
        p.h[(size_t)row*HID + ccol + l15]      = v0;
        p.h[(size_t)row*HID + ccol + 16 + l15] = v1;
        p.xh[(size_t)row*HID + ccol + l15]      = f2b(v0);
        p.xh[(size_t)row*HID + ccol + 16 + l15] = f2b(v1);
      }
    }
  }
  gg.sync();

  // ---- 4 layers ----
  const unsigned* xhu = (const unsigned*)p.xh;
  unsigned* cbu = (unsigned*)p.cbt;
  for (int lay = 0; lay < 4; ++lay){
    // --- agg: cbt[v] = mean of xh[src] (1 wave per node) ---
    {
      const int wgid = blockIdx.x*4 + (tid>>6);
      const int nwv  = gridDim.x*4;
      for (int node = wgid; node < p.N; node += nwv){
        int e0 = p.offs[node], e1 = p.offs[node+1];
        float ax = 0.f, ay = 0.f;
        int e = e0;
        for (; e + 7 < e1; e += 8){
          int a0=p.ssrc[e],a1=p.ssrc[e+1],a2=p.ssrc[e+2],a3=p.ssrc[e+3];
          int a4=p.ssrc[e+4],a5=p.ssrc[e+5],a6=p.ssrc[e+6],a7=p.ssrc[e+7];
          unsigned u0=xhu[(size_t)a0*64+l], u1=xhu[(size_t)a1*64+l];
          unsigned u2=xhu[(size_t)a2*64+l], u3=xhu[(size_t)a3*64+l];
          unsigned u4=xhu[(size_t)a4*64+l], u5=xhu[(size_t)a5*64+l];
          unsigned u6=xhu[(size_t)a6*64+l], u7=xhu[(size_t)a7*64+l];
          ax += ((blo(u0)+blo(u1))+(blo(u2)+blo(u3))) + ((blo(u4)+blo(u5))+(blo(u6)+blo(u7)));
          ay += ((bhi(u0)+bhi(u1))+(bhi(u2)+bhi(u3))) + ((bhi(u4)+bhi(u5))+(bhi(u6)+bhi(u7)));
        }
        for (; e + 1 < e1; e += 2){
          unsigned u0 = xhu[(size_t)p.ssrc[e]*64 + l];
          unsigned u1 = xhu[(size_t)p.ssrc[e+1]*64 + l];
          ax += blo(u0) + blo(u1);
          ay += bhi(u0) + bhi(u1);
        }
        if (e < e1){
          unsigned u0 = xhu[(size_t)p.ssrc[e]*64 + l];
          ax += blo(u0); ay += bhi(u0);
        }
        float id = p.invd[node];
        cbu[(size_t)node*64 + l] = pack2(ax*id, ay*id);
      }
    }
    gg.sync();

    // --- gemm + L2norm + relu + BN partials ---
    {
      const unsigned short* Wb = p.Wsb + (size_t)lay*HID*TWO_HID;
      const float* bv = p.bs + (size_t)lay*HID;
      float* cs = p.colsums + (size_t)lay*256;
      short8 bfr[2][8];
      #pragma unroll
      for (int t=0;t<2;t++){
        #pragma unroll
        for (int s=0;s<8;s++)
          bfr[t][s] = *(const short8*)(Wb + (size_t)(ccol + t*16 + l15)*TWO_HID + s*32 + lhi*8);
      }
      const float bias0 = bv[ccol + l15];
      const float bias1 = bv[ccol + 16 + l15];
      float s1a=0.f, s2a=0.f, s1b=0.f, s2b=0.f;
      int pp = 0;
      for (int tile = blockIdx.x; tile < p.Ntiles; tile += gridDim.x, pp ^= 1){
        const int row0 = tile * 16;
        f32x4 acc0 = {0.f,0.f,0.f,0.f}, acc1 = {0.f,0.f,0.f,0.f};
        // batch 1: xh half (keeps af live-range small for VGPR budget)
        #pragma unroll
        for (int s=0;s<4;s++){
          short8 a = *(const short8*)(p.xh + (size_t)(row0 + l15)*HID + s*32 + lhi*8);
          acc0 = __builtin_amdgcn_mfma_f32_16x16x32_bf16(a, bfr[0][s], acc0, 0,0,0);
          acc1 = __builtin_amdgcn_mfma_f32_16x16x32_bf16(a, bfr[1][s], acc1, 0,0,0);
        }
        // batch 2: cbt half
        #pragma unroll
        for (int s=0;s<4;s++){
          short8 a = *(const short8*)(p.cbt + (size_t)(row0 + l15)*HID + s*32 + lhi*8);
          acc0 = __builtin_amdgcn_mfma_f32_16x16x32_bf16(a, bfr[0][4+s], acc0, 0,0,0);
          acc1 = __builtin_amdgcn_mfma_f32_16x16x32_bf16(a, bfr[1][4+s], acc1, 0,0,0);
        }
        float v0[4], v1[4], pr[4];
        #pragma unroll
        for (int r=0;r<4;r++){
          v0[r] = acc0[r] + bias0;
          v1[r] = acc1[r] + bias1;
          pr[r] = v0[r]*v0[r] + v1[r]*v1[r];
        }
        #pragma unroll
        for (int m=1;m<=8;m<<=1){
          #pragma unroll
          for (int r=0;r<4;r++) pr[r] += __shfl_xor(pr[r], m, 64);
        }
        if (l15 == 0){
          #pragma unroll
          for (int r=0;r<4;r++) rowss[pp][lhi*4+r][w] = pr[r];
        }
        __syncthreads();
        #pragma unroll
        for (int r=0;r<4;r++){
          const int i = lhi*4 + r;
          f32x4 q = *(const f32x4*)&rowss[pp][i][0];
          float ss = (q[0]+q[1]) + (q[2]+q[3]);
          float sc = 1.f / fmaxf(sqrtf(ss), 1e-12f);
          float z0 = fmaxf(v0[r]*sc, 0.f);
          float z1 = fmaxf(v1[r]*sc, 0.f);
          p.zb[(size_t)(row0+i)*HID + ccol + l15]      = z0;
          p.zb[(size_t)(row0+i)*HID + ccol + 16 + l15] = z1;
          s1a += z0; s2a += z0*z0;
          s1b += z1; s2b += z1*z1;
        }
      }
      s1a += __shfl_xor(s1a,16,64); s1a += __shfl_xor(s1a,32,64);
      s2a += __shfl_xor(s2a,16,64); s2a += __shfl_xor(s2a,32,64);
      s1b += __shfl_xor(s1b,16,64); s1b += __shfl_xor(s1b,32,64);
      s2b += __shfl_xor(s2b,16,64); s2b += __shfl_xor(s2b,32,64);
      if (lhi == 0){
        atomicAdd(&cs[ccol + l15],            s1a);
        atomicAdd(&cs[128 + ccol + l15],      s2a);
        atomicAdd(&cs[ccol + 16 + l15],       s1b);
        atomicAdd(&cs[128 + ccol + 16 + l15], s2b);
      }
    }
    gg.sync();

    // --- bn stats inline + apply + residual + refresh mirror ---
    {
      const float* cs = p.colsums + (size_t)lay*256;
      const float* gmv = p.gam + (size_t)lay*HID;
      const float* btv = p.bet + (size_t)lay*HID;
      const float invN = 1.0f / (float)p.N;
      unsigned* xw = (unsigned*)p.xh;
      const int tot = p.N * 64;
      for (int i = gid0; i < tot; i += gsz){
        int j = i & 63;
        float2 s1 = ((const float2*)cs)[j];
        float2 s2 = ((const float2*)(cs + 128))[j];
        float2 g  = ((const float2*)gmv)[j];
        float2 bt = ((const float2*)btv)[j];
        float mux = s1.x*invN,           muy = s1.y*invN;
        float vax = s2.x*invN - mux*mux, vay = s2.y*invN - muy*muy;
        float scx = g.x * rsqrtf(vax + 1e-5f), scy = g.y * rsqrtf(vay + 1e-5f);
        float shx = bt.x - mux*scx,            shy = bt.y - muy*scy;
        float2 zv = ((const float2*)p.zb)[i];
        float2 hv = ((const float2*)p.h)[i];
        float nx = fmaf(zv.x, scx, hv.x + shx);
        float ny = fmaf(zv.y, scy, hv.y + shy);
        ((float2*)p.h)[i] = make_float2(nx, ny);
        xw[i] = pack2(nx, ny);
      }
    }
    if (lay != 3) gg.sync();
  }
}

// ================= legacy fallback kernels (R6 path) =================
__global__ void k_deg(const int* __restrict__ dst, int* __restrict__ deg, int E){
  int e = blockIdx.x*blockDim.x + threadIdx.x;
  if (e < E) atomicAdd(&deg[dst[e]], 1);
}
__global__ __launch_bounds__(256) void k_scan1(const int* __restrict__ deg, int* __restrict__ loc,
                                               int* __restrict__ bsum, int N){
  const int tid = threadIdx.x;
  const int i = blockIdx.x*256 + tid;
  const int lane = tid & 63, wv = tid >> 6;
  int v = (i < N) ? deg[i] : 0;
  int s = v;
  #pragma unroll
  for (int m=1; m<64; m<<=1){
    int t = __shfl_up(s, m, 64);
    if (lane >= m) s += t;
  }
  __shared__ int wsum[4];
  if (lane == 63) wsum[wv] = s;
  __syncthreads();
  if (tid == 0){
    int a = 0;
    #pragma unroll
    for (int q=0;q<4;q++){ int t = wsum[q]; wsum[q] = a; a += t; }
    bsum[blockIdx.x] = a;
  }
  __syncthreads();
  if (i < N) loc[i] = s - v + wsum[wv];
}
__global__ __launch_bounds__(256) void k_scan2(int* __restrict__ bsum, int nb){
  const int tid = threadIdx.x;
  const int lane = tid & 63, wv = tid >> 6;
  int v = (tid < nb) ? bsum[tid] : 0;
  int s = v;
  #pragma unroll
  for (int m=1; m<64; m<<=1){
    int t = __shfl_up(s, m, 64);
    if (lane >= m) s += t;
  }
  __shared__ int wsum[4];
  if (lane == 63) wsum[wv] = s;
  __syncthreads();
  if (tid == 0){
    int a = 0;
    #pragma unroll
    for (int q=0;q<4;q++){ int t = wsum[q]; wsum[q] = a; a += t; }
  }
  __syncthreads();
  if (tid < nb) bsum[tid] = s - v + wsum[wv];
}
__global__ __launch_bounds__(256) void k_scan3(const int* __restrict__ deg, const int* __restrict__ loc,
                                               const int* __restrict__ bsum, int* __restrict__ offs,
                                               float* __restrict__ invd, int N, int E){
  const int i = blockIdx.x*256 + threadIdx.x;
  if (i < N){
    offs[i] = loc[i] + bsum[blockIdx.x];
    int d = deg[i];
    invd[i] = 1.0f / (float)(d>1?d:1);
  }
  if (i == 0) offs[N] = E;
}
__global__ void k_fill(const int* __restrict__ src, const int* __restrict__ dst,
                       const int* __restrict__ offs, int* __restrict__ cursor,
                       int* __restrict__ ssrc, int E){
  int e = blockIdx.x*blockDim.x + threadIdx.x;
  if (e < E){
    int d = dst[e];
    int pos = offs[d] + atomicAdd(&cursor[d], 1);
    ssrc[pos] = src[e];
  }
}
__global__ void k_wcvt(const float* __restrict__ Wemb, const float* __restrict__ Ws,
                       unsigned short* __restrict__ Wembb, unsigned short* __restrict__ Wsb,
                       int nEmb, int nWs){
  int i = blockIdx.x*blockDim.x + threadIdx.x;
  if (i < nEmb) Wembb[i] = f2b(Wemb[i]);
  else if (i < nEmb + nWs) Wsb[i - nEmb] = f2b(Ws[i - nEmb]);
}
__global__ __launch_bounds__(256) void k_embed(const float* __restrict__ h0, const unsigned short* __restrict__ Wb,
                                               const float* __restrict__ b, float* __restrict__ h,
                                               unsigned short* __restrict__ xh, int Ntiles){
  const int tid = threadIdx.x;
  const int w = tid >> 6, l = tid & 63;
  const int l15 = l & 15, lhi = l >> 4;
  const int cb = w * 32;
  short8 bf[2][4];
  #pragma unroll
  for (int t=0;t<2;t++){
    #pragma unroll
    for (int s=0;s<4;s++)
      bf[t][s] = *(const short8*)(Wb + (size_t)(cb + t*16 + l15)*HID + s*32 + lhi*8);
  }
  const float bias0 = b[cb + l15];
  const float bias1 = b[cb + 16 + l15];
  for (int tile = blockIdx.x; tile < Ntiles; tile += gridDim.x){
    const int row0 = tile * 16;
    f32x4 acc0 = {0.f,0.f,0.f,0.f}, acc1 = {0.f,0.f,0.f,0.f};
    #pragma unroll
    for (int s=0;s<4;s++){
      const float* ap = h0 + (size_t)(row0 + l15)*HID + s*32 + lhi*8;
      float4 x0 = *(const float4*)ap;
      float4 x1 = *(const float4*)(ap + 4);
      short8 f;
      f[0]=(short)f2b(x0.x); f[1]=(short)f2b(x0.y); f[2]=(short)f2b(x0.z); f[3]=(short)f2b(x0.w);
      f[4]=(short)f2b(x1.x); f[5]=(short)f2b(x1.y); f[6]=(short)f2b(x1.z); f[7]=(short)f2b(x1.w);
      acc0 = __builtin_amdgcn_mfma_f32_16x16x32_bf16(f, bf[0][s], acc0, 0,0,0);
      acc1 = __builtin_amdgcn_mfma_f32_16x16x32_bf16(f, bf[1][s], acc1, 0,0,0);
    }
    #pragma unroll
    for (int r=0;r<4;r++){
      const int row = row0 + lhi*4 + r;
      float v0 = acc0[r] + bias0;
      float v1 = acc1[r] + bias1;
      h[(size_t)row*HID + cb + l15]      = v0;
      h[(size_t)row*HID + cb + 16 + l15] = v1;
      xh[(size_t)row*HID + cb + l15]      = f2b(v0);
      xh[(size_t)row*HID + cb + 16 + l15] = f2b(v1);
    }
  }
}
__global__ __launch_bounds__(256) void k_agg(const unsigned* __restrict__ xhu, const int* __restrict__ offs,
                                             const int* __restrict__ ssrc, const float* __restrict__ invd,
                                             unsigned* __restrict__ cbu, int N){
  int gid = blockIdx.x*blockDim.x + threadIdx.x;
  int node = gid >> 6;
  int lane = gid & 63;
  if (node >= N) return;
  int e0 = offs[node], e1 = offs[node+1];
  float ax = 0.f, ay = 0.f;
  int e = e0;
  for (; e + 7 < e1; e += 8){
    int a0=ssrc[e],a1=ssrc[e+1],a2=ssrc[e+2],a3=ssrc[e+3];
    int a4=ssrc[e+4],a5=ssrc[e+5],a6=ssrc[e+6],a7=ssrc[e+7];
    unsigned u0=xhu[(size_t)a0*64+lane], u1=xhu[(size_t)a1*64+lane];
    unsigned u2=xhu[(size_t)a2*64+lane], u3=xhu[(size_t)a3*64+lane];
    unsigned u4=xhu[(size_t)a4*64+lane], u5=xhu[(size_t)a5*64+lane];
    unsigned u6=xhu[(size_t)a6*64+lane], u7=xhu[(size_t)a7*64+lane];
    ax += ((blo(u0)+blo(u1))+(blo(u2)+blo(u3))) + ((blo(u4)+blo(u5))+(blo(u6)+blo(u7)));
    ay += ((bhi(u0)+bhi(u1))+(bhi(u2)+bhi(u3))) + ((bhi(u4)+bhi(u5))+(bhi(u6)+bhi(u7)));
  }
  for (; e + 1 < e1; e += 2){
    unsigned u0 = xhu[(size_t)ssrc[e]*64 + lane];
    unsigned u1 = xhu[(size_t)ssrc[e+1]*64 + lane];
    ax += blo(u0) + blo(u1);
    ay += bhi(u0) + bhi(u1);
  }
  if (e < e1){
    unsigned u0 = xhu[(size_t)ssrc[e]*64 + lane];
    ax += blo(u0); ay += bhi(u0);
  }
  float id = invd[node];
  cbu[(size_t)node*64 + lane] = pack2(ax*id, ay*id);
}
__global__ __launch_bounds__(256) void k_gemm(const unsigned short* __restrict__ xh,
                                              const unsigned short* __restrict__ cbt,
                                              const unsigned short* __restrict__ Wb, const float* __restrict__ b,
                                              float* __restrict__ zb, float* __restrict__ colsums, int Ntiles){
  __shared__ float rowss[2][16][4];
  const int tid = threadIdx.x;
  const int w = tid >> 6, l = tid & 63;
  const int l15 = l & 15, lhi = l >> 4;
  const int cb = w * 32;
  short8 bf[2][8];
  #pragma unroll
  for (int t=0;t<2;t++){
    #pragma unroll
    for (int s=0;s<8;s++)
      bf[t][s] = *(const short8*)(Wb + (size_t)(cb + t*16 + l15)*TWO_HID + s*32 + lhi*8);
  }
  const float bias0 = b[cb + l15];
  const float bias1 = b[cb + 16 + l15];
  float s1a = 0.f, s2a = 0.f, s1b = 0.f, s2b = 0.f;
  int pp = 0;
  for (int tile = blockIdx.x; tile < Ntiles; tile += gridDim.x, pp ^= 1){
    const int row0 = tile * 16;
    f32x4 acc0 = {0.f,0.f,0.f,0.f}, acc1 = {0.f,0.f,0.f,0.f};
    #pragma unroll
    for (int s=0;s<4;s++){
      short8 a = *(const short8*)(xh + (size_t)(row0 + l15)*HID + s*32 + lhi*8);
      acc0 = __builtin_amdgcn_mfma_f32_16x16x32_bf16(a, bf[0][s], acc0, 0,0,0);
      acc1 = __builtin_amdgcn_mfma_f32_16x16x32_bf16(a, bf[1][s], acc1, 0,0,0);
    }
    #pragma unroll
    for (int s=0;s<4;s++){
      short8 a = *(const short8*)(cbt + (size_t)(row0 + l15)*HID + s*32 + lhi*8);
      acc0 = __builtin_amdgcn_mfma_f32_16x16x32_bf16(a, bf[0][4+s], acc0, 0,0,0);
      acc1 = __builtin_amdgcn_mfma_f32_16x16x32_bf16(a, bf[1][4+s], acc1, 0,0,0);
    }
    float v0[4], v1[4], pr[4];
    #pragma unroll
    for (int r=0;r<4;r++){
      v0[r] = acc0[r] + bias0;
      v1[r] = acc1[r] + bias1;
      pr[r] = v0[r]*v0[r] + v1[r]*v1[r];
    }
    #pragma unroll
    for (int m=1;m<=8;m<<=1){
      #pragma unroll
      for (int r=0;r<4;r++) pr[r] += __shfl_xor(pr[r], m, 64);
    }
    if (l15 == 0){
      #pragma unroll
      for (int r=0;r<4;r++) rowss[pp][lhi*4+r][w] = pr[r];
    }
    __syncthreads();
    #pragma unroll
    for (int r=0;r<4;r++){
      const int i = lhi*4 + r;
      f32x4 q = *(const f32x4*)&rowss[pp][i][0];
      float ss = (q[0]+q[1]) + (q[2]+q[3]);
      float sc = 1.f / fmaxf(sqrtf(ss), 1e-12f);
      float z0 = fmaxf(v0[r]*sc, 0.f);
      float z1 = fmaxf(v1[r]*sc, 0.f);
      zb[(size_t)(row0+i)*HID + cb + l15]      = z0;
      zb[(size_t)(row0+i)*HID + cb + 16 + l15] = z1;
      s1a += z0; s2a += z0*z0;
      s1b += z1; s2b += z1*z1;
    }
  }
  s1a += __shfl_xor(s1a,16,64); s1a += __shfl_xor(s1a,32,64);
  s2a += __shfl_xor(s2a,16,64); s2a += __shfl_xor(s2a,32,64);
  s1b += __shfl_xor(s1b,16,64); s1b += __shfl_xor(s1b,32,64);
  s2b += __shfl_xor(s2b,16,64); s2b += __shfl_xor(s2b,32,64);
  if (lhi == 0){
    atomicAdd(&colsums[cb + l15],            s1a);
    atomicAdd(&colsums[128 + cb + l15],      s2a);
    atomicAdd(&colsums[cb + 16 + l15],       s1b);
    atomicAdd(&colsums[128 + cb + 16 + l15], s2b);
  }
}
__global__ __launch_bounds__(256) void k_bn(const float* __restrict__ z, const float* __restrict__ colsums,
                                            const float* __restrict__ gamma, const float* __restrict__ beta,
                                            float* __restrict__ h, unsigned* __restrict__ xhu,
                                            int Nh, float invN){
  int i = blockIdx.x*blockDim.x + threadIdx.x;
  if (i >= Nh) return;
  int j = i & 63;
  float2 s1 = ((const float2*)colsums)[j];
  float2 s2 = ((const float2*)(colsums + 128))[j];
  float2 g  = ((const float2*)gamma)[j];
  float2 bt = ((const float2*)beta)[j];
  float mux = s1.x*invN,           muy = s1.y*invN;
  float vax = s2.x*invN - mux*mux, vay = s2.y*invN - muy*muy;
  float scx = g.x * rsqrtf(vax + 1e-5f), scy = g.y * rsqrtf(vay + 1e-5f);
  float shx = bt.x - mux*scx,            shy = bt.y - muy*scy;
  float2 zv = ((const float2*)z)[i];
  float2 hv = ((const float2*)h)[i];
  float nx = fmaf(zv.x, scx, hv.x + shx);
  float ny = fmaf(zv.y, scy, hv.y + shy);
  ((float2*)h)[i] = make_float2(nx, ny);
  xhu[i] = pack2(nx, ny);
}

extern "C" void kernel_launch(void* const* d_in, const int* in_sizes, int n_in,
                              void* d_out, int out_size, void* d_ws, size_t ws_size,
                              hipStream_t stream){
  const float* h0   = (const float*)d_in[0];
  const int*   src  = (const int*)d_in[1];
  const int*   dst  = (const int*)d_in[2];
  const float* Wemb = (const float*)d_in[3];
  const float* bemb = (const float*)d_in[4];
  const float* Ws   = (const float*)d_in[5];
  const float* bs   = (const float*)d_in[6];
  const float* gam  = (const float*)d_in[7];
  const float* bet  = (const float*)d_in[8];
  const int N = in_sizes[0] / HID;
  const int E = in_sizes[1];
  const int Ntiles = N / 16;
  const int NB = (N + 255) / 256;
  float* h = (float*)d_out;

  char* ws = (char*)d_ws;
  size_t off = 0;
  auto alloc = [&](size_t bytes)->char*{
    char* p = ws + off;
    off = (off + bytes + 255) & ~(size_t)255;
    return p;
  };
  int*   deg      = (int*)  alloc((size_t)N*4);        // deg,cursor,colsums contiguous -> one memset
  int*   cursor   = (int*)  alloc((size_t)N*4);
  float* colsums  = (float*)alloc(4*256*4);
  int*   offs     = (int*)  alloc((size_t)(N+1)*4);
  int*   loc      = (int*)  alloc((size_t)N*4);
  int*   bsum     = (int*)  alloc((size_t)NB*4);
  float* invd     = (float*)alloc((size_t)N*4);
  int*   ssrc     = (int*)  alloc((size_t)E*4);
  unsigned short* Wembb = (unsigned short*)alloc((size_t)NEMB*2);
  unsigned short* Wsb   = (unsigned short*)alloc((size_t)NWS*2);
  unsigned short* xh    = (unsigned short*)alloc((size_t)N*HID*2);
  unsigned short* cbt   = (unsigned short*)alloc((size_t)N*HID*2);
  float* zb       = (float*)alloc((size_t)N*HID*4);

  // zero deg + cursor + colsums in one memset node
  hipMemsetAsync(deg, 0, (size_t)2*N*4 + 4*256*4, stream);

  MegaParams p;
  p.h0 = h0; p.src = src; p.dst = dst;
  p.Wemb = Wemb; p.bemb = bemb; p.Ws = Ws; p.bs = bs; p.gam = gam; p.bet = bet;
  p.h = h;
  p.deg = deg; p.cursor = cursor; p.colsums = colsums; p.offs = offs; p.loc = loc; p.bsum = bsum;
  p.invd = invd; p.ssrc = ssrc;
  p.Wembb = Wembb; p.Wsb = Wsb; p.xh = xh; p.cbt = cbt; p.zb = zb;
  p.N = N; p.E = E; p.Ntiles = Ntiles; p.NB = NB;

  void* args[] = { &p };
  hipError_t cerr = hipLaunchCooperativeKernel((const void*)k_mega, dim3(1024), dim3(256),
                                               args, 0, stream);
  if (cerr != hipSuccess){
    // legacy multi-launch fallback (R6 path)
    hipLaunchKernelGGL(k_deg,   dim3((E+255)/256),   dim3(256), 0, stream, dst, deg, E);
    hipLaunchKernelGGL(k_scan1, dim3(NB),  dim3(256), 0, stream, deg, loc, bsum, N);
    hipLaunchKernelGGL(k_scan2, dim3(1),   dim3(256), 0, stream, bsum, NB);
    hipLaunchKernelGGL(k_scan3, dim3(NB),  dim3(256), 0, stream, deg, loc, bsum, offs, invd, N, E);
    hipLaunchKernelGGL(k_fill,  dim3((E+255)/256),   dim3(256), 0, stream, src, dst, offs, cursor, ssrc, E);
    hipLaunchKernelGGL(k_wcvt,  dim3((NEMB+NWS+255)/256), dim3(256), 0, stream, Wemb, Ws, Wembb, Wsb, NEMB, NWS);
    hipLaunchKernelGGL(k_embed, dim3(512), dim3(256), 0, stream, h0, Wembb, bemb, h, xh, Ntiles);
    for (int l=0;l<4;l++){
      hipLaunchKernelGGL(k_agg, dim3((N*64+255)/256), dim3(256), 0, stream,
                         (const unsigned*)xh, offs, ssrc, invd, (unsigned*)cbt, N);
      hipLaunchKernelGGL(k_gemm, dim3(512), dim3(256), 0, stream,
                         xh, cbt, Wsb + (size_t)l*HID*TWO_HID, bs + (size_t)l*HID,
                         zb, colsums + (size_t)l*256, Ntiles);
      hipLaunchKernelGGL(k_bn, dim3((N*64+255)/256), dim3(256), 0, stream,
                         zb, colsums + (size_t)l*256, gam + (size_t)l*HID, bet + (size_t)l*HID,
                         h, (unsigned*)xh, N*64, 1.0f/(float)N);
    }
  }
}

// Round 8
// 867.890 us; speedup vs baseline: 2.9366x; 2.9366x over previous
//
#include <hip/hip_runtime.h>
#include <hip/hip_cooperative_groups.h>

namespace cg = cooperative_groups;

#define HID 128
#define TWO_HID 256
#define NEMB (HID*HID)
#define NWS  (4*HID*TWO_HID)

typedef __attribute__((ext_vector_type(8))) short short8;
typedef __attribute__((ext_vector_type(4))) float f32x4;

__device__ inline unsigned short f2b(float f){
  unsigned u = __float_as_uint(f);
  unsigned r = u + 0x7FFFu + ((u >> 16) & 1u);   // RNE
  return (unsigned short)(r >> 16);
}
__device__ inline unsigned pack2(float lo, float hi){
  return (unsigned)f2b(lo) | ((unsigned)f2b(hi) << 16);
}
__device__ inline float blo(unsigned u){ return __uint_as_float(u << 16); }
__device__ inline float bhi(unsigned u){ return __uint_as_float(u & 0xFFFF0000u); }

// ================= cooperative CSR-build kernel (all phases <32 VGPR) =================
struct CsrParams {
  const int* src; const int* dst;
  const float* Wemb; const float* Ws;
  unsigned short* Wembb; unsigned short* Wsb;
  int* deg; int* cursor; int* offs; int* loc; int* bsum;
  float* invd; int* ssrc;
  int N, E, NB;
};

__global__ __launch_bounds__(256, 4) void k_csr(CsrParams p){
  cg::grid_group gg = cg::this_grid();
  __shared__ int wsum[4];
  const int tid  = threadIdx.x;
  const int gsz  = gridDim.x * 256;
  const int gid0 = blockIdx.x * 256 + tid;
  const int w = tid >> 6, l = tid & 63;

  // ph0: weight f32 -> bf16
  for (int i = gid0; i < NEMB + NWS; i += gsz){
    if (i < NEMB) p.Wembb[i] = f2b(p.Wemb[i]);
    else          p.Wsb[i - NEMB] = f2b(p.Ws[i - NEMB]);
  }
  // ph1: degree count (no sync needed vs ph0: disjoint data, but deg zeroed by host memset)
  for (int e = gid0; e < p.E; e += gsz) atomicAdd(&p.deg[p.dst[e]], 1);
  gg.sync();

  // ph2: per-256-chunk scan + chunk sums
  for (int c = blockIdx.x; c < p.NB; c += gridDim.x){
    const int i = c*256 + tid;
    int v = (i < p.N) ? p.deg[i] : 0;
    int s = v;
    #pragma unroll
    for (int m=1; m<64; m<<=1){
      int t = __shfl_up(s, m, 64);
      if (l >= m) s += t;
    }
    if (l == 63) wsum[w] = s;
    __syncthreads();
    if (tid == 0){
      int a = 0;
      #pragma unroll
      for (int q=0;q<4;q++){ int t = wsum[q]; wsum[q] = a; a += t; }
      p.bsum[c] = a;
    }
    __syncthreads();
    if (i < p.N) p.loc[i] = s - v + wsum[w];
    __syncthreads();
  }
  gg.sync();

  // ph3: scan chunk sums (NB<=256), block 0
  if (blockIdx.x == 0){
    int v = (tid < p.NB) ? p.bsum[tid] : 0;
    int s = v;
    #pragma unroll
    for (int m=1; m<64; m<<=1){
      int t = __shfl_up(s, m, 64);
      if (l >= m) s += t;
    }
    if (l == 63) wsum[w] = s;
    __syncthreads();
    if (tid == 0){
      int a = 0;
      #pragma unroll
      for (int q=0;q<4;q++){ int t = wsum[q]; wsum[q] = a; a += t; }
    }
    __syncthreads();
    if (tid < p.NB) p.bsum[tid] = s - v + wsum[w];
  }
  gg.sync();

  // ph4: offs = loc + bsum[chunk]; invd (deg0 sentinel = -1)
  for (int i = gid0; i < p.N; i += gsz){
    p.offs[i] = p.loc[i] + p.bsum[i >> 8];
    int d = p.deg[i];
    p.invd[i] = (d > 0) ? 1.0f / (float)d : -1.0f;
  }
  if (gid0 == 0) p.offs[p.N] = p.E;
  gg.sync();

  // ph5: counting-sort fill
  for (int e = gid0; e < p.E; e += gsz){
    int d = p.dst[e];
    int pos = p.offs[d] + atomicAdd(&p.cursor[d], 1);
    p.ssrc[pos] = p.src[e];
  }
}

// ================= fallback CSR kernels =================
__global__ void k_deg(const int* __restrict__ dst, int* __restrict__ deg, int E){
  int e = blockIdx.x*blockDim.x + threadIdx.x;
  if (e < E) atomicAdd(&deg[dst[e]], 1);
}
__global__ __launch_bounds__(256) void k_scan1(const int* __restrict__ deg, int* __restrict__ loc,
                                               int* __restrict__ bsum, int N){
  const int tid = threadIdx.x;
  const int i = blockIdx.x*256 + tid;
  const int lane = tid & 63, wv = tid >> 6;
  int v = (i < N) ? deg[i] : 0;
  int s = v;
  #pragma unroll
  for (int m=1; m<64; m<<=1){
    int t = __shfl_up(s, m, 64);
    if (lane >= m) s += t;
  }
  __shared__ int wsum[4];
  if (lane == 63) wsum[wv] = s;
  __syncthreads();
  if (tid == 0){
    int a = 0;
    #pragma unroll
    for (int q=0;q<4;q++){ int t = wsum[q]; wsum[q] = a; a += t; }
    bsum[blockIdx.x] = a;
  }
  __syncthreads();
  if (i < N) loc[i] = s - v + wsum[wv];
}
__global__ __launch_bounds__(256) void k_scan2(int* __restrict__ bsum, int nb){
  const int tid = threadIdx.x;
  const int lane = tid & 63, wv = tid >> 6;
  int v = (tid < nb) ? bsum[tid] : 0;
  int s = v;
  #pragma unroll
  for (int m=1; m<64; m<<=1){
    int t = __shfl_up(s, m, 64);
    if (lane >= m) s += t;
  }
  __shared__ int wsum[4];
  if (lane == 63) wsum[wv] = s;
  __syncthreads();
  if (tid == 0){
    int a = 0;
    #pragma unroll
    for (int q=0;q<4;q++){ int t = wsum[q]; wsum[q] = a; a += t; }
  }
  __syncthreads();
  if (tid < nb) bsum[tid] = s - v + wsum[wv];
}
__global__ __launch_bounds__(256) void k_scan3(const int* __restrict__ deg, const int* __restrict__ loc,
                                               const int* __restrict__ bsum, int* __restrict__ offs,
                                               float* __restrict__ invd, int N, int E){
  const int i = blockIdx.x*256 + threadIdx.x;
  if (i < N){
    offs[i] = loc[i] + bsum[blockIdx.x];
    int d = deg[i];
    invd[i] = (d > 0) ? 1.0f / (float)d : -1.0f;
  }
  if (i == 0) offs[N] = E;
}
__global__ void k_fill(const int* __restrict__ src, const int* __restrict__ dst,
                       const int* __restrict__ offs, int* __restrict__ cursor,
                       int* __restrict__ ssrc, int E){
  int e = blockIdx.x*blockDim.x + threadIdx.x;
  if (e < E){
    int d = dst[e];
    int pos = offs[d] + atomicAdd(&cursor[d], 1);
    ssrc[pos] = src[e];
  }
}
__global__ void k_wcvt(const float* __restrict__ Wemb, const float* __restrict__ Ws,
                       unsigned short* __restrict__ Wembb, unsigned short* __restrict__ Wsb,
                       int nEmb, int nWs){
  int i = blockIdx.x*blockDim.x + threadIdx.x;
  if (i < nEmb) Wembb[i] = f2b(Wemb[i]);
  else if (i < nEmb + nWs) Wsb[i - nEmb] = f2b(Ws[i - nEmb]);
}

// ================= input embedding (MFMA bf16) =================
__global__ __launch_bounds__(256) void k_embed(const float* __restrict__ h0, const unsigned short* __restrict__ Wb,
                                               const float* __restrict__ b, float* __restrict__ h,
                                               unsigned short* __restrict__ xh, int Ntiles){
  const int tid = threadIdx.x;
  const int w = tid >> 6, l = tid & 63;
  const int l15 = l & 15, lhi = l >> 4;
  const int cb = w * 32;
  short8 bf[2][4];
  #pragma unroll
  for (int t=0;t<2;t++){
    #pragma unroll
    for (int s=0;s<4;s++)
      bf[t][s] = *(const short8*)(Wb + (size_t)(cb + t*16 + l15)*HID + s*32 + lhi*8);
  }
  const float bias0 = b[cb + l15];
  const float bias1 = b[cb + 16 + l15];
  for (int tile = blockIdx.x; tile < Ntiles; tile += gridDim.x){
    const int row0 = tile * 16;
    f32x4 acc0 = {0.f,0.f,0.f,0.f}, acc1 = {0.f,0.f,0.f,0.f};
    #pragma unroll
    for (int s=0;s<4;s++){
      const float* ap = h0 + (size_t)(row0 + l15)*HID + s*32 + lhi*8;
      float4 x0 = *(const float4*)ap;
      float4 x1 = *(const float4*)(ap + 4);
      short8 f;
      f[0]=(short)f2b(x0.x); f[1]=(short)f2b(x0.y); f[2]=(short)f2b(x0.z); f[3]=(short)f2b(x0.w);
      f[4]=(short)f2b(x1.x); f[5]=(short)f2b(x1.y); f[6]=(short)f2b(x1.z); f[7]=(short)f2b(x1.w);
      acc0 = __builtin_amdgcn_mfma_f32_16x16x32_bf16(f, bf[0][s], acc0, 0,0,0);
      acc1 = __builtin_amdgcn_mfma_f32_16x16x32_bf16(f, bf[1][s], acc1, 0,0,0);
    }
    #pragma unroll
    for (int r=0;r<4;r++){
      const int row = row0 + lhi*4 + r;
      float v0 = acc0[r] + bias0;
      float v1 = acc1[r] + bias1;
      h[(size_t)row*HID + cb + l15]      = v0;
      h[(size_t)row*HID + cb + 16 + l15] = v1;
      xh[(size_t)row*HID + cb + l15]      = f2b(v0);
      xh[(size_t)row*HID + cb + 16 + l15] = f2b(v1);
    }
  }
}

// ================= layer-1 aggregation: cbt[v] = mean of xh[nbrs] =================
__global__ __launch_bounds__(256) void k_agg(const unsigned* __restrict__ xhu, const int* __restrict__ offs,
                                             const int* __restrict__ ssrc, const float* __restrict__ invd,
                                             unsigned* __restrict__ cbu, int N){
  int gid = blockIdx.x*blockDim.x + threadIdx.x;
  int node = gid >> 6;
  int lane = gid & 63;
  if (node >= N) return;
  int e0 = offs[node], e1 = offs[node+1];
  float ax = 0.f, ay = 0.f;
  int e = e0;
  for (; e + 7 < e1; e += 8){
    int a0=ssrc[e],a1=ssrc[e+1],a2=ssrc[e+2],a3=ssrc[e+3];
    int a4=ssrc[e+4],a5=ssrc[e+5],a6=ssrc[e+6],a7=ssrc[e+7];
    unsigned u0=xhu[(size_t)a0*64+lane], u1=xhu[(size_t)a1*64+lane];
    unsigned u2=xhu[(size_t)a2*64+lane], u3=xhu[(size_t)a3*64+lane];
    unsigned u4=xhu[(size_t)a4*64+lane], u5=xhu[(size_t)a5*64+lane];
    unsigned u6=xhu[(size_t)a6*64+lane], u7=xhu[(size_t)a7*64+lane];
    ax += ((blo(u0)+blo(u1))+(blo(u2)+blo(u3))) + ((blo(u4)+blo(u5))+(blo(u6)+blo(u7)));
    ay += ((bhi(u0)+bhi(u1))+(bhi(u2)+bhi(u3))) + ((bhi(u4)+bhi(u5))+(bhi(u6)+bhi(u7)));
  }
  for (; e + 1 < e1; e += 2){
    unsigned u0 = xhu[(size_t)ssrc[e]*64 + lane];
    unsigned u1 = xhu[(size_t)ssrc[e+1]*64 + lane];
    ax += blo(u0) + blo(u1);
    ay += bhi(u0) + bhi(u1);
  }
  if (e < e1){
    unsigned u0 = xhu[(size_t)ssrc[e]*64 + lane];
    ax += blo(u0); ay += bhi(u0);
  }
  float id = invd[node];       // deg0: sums are 0, sign irrelevant
  float ida = fabsf(id);
  cbu[(size_t)node*64 + lane] = pack2(ax*ida*(id>0.f?1.f:0.f), ay*ida*(id>0.f?1.f:0.f));
}

// ================= layer GEMM (MFMA bf16) + L2norm + relu + BN partials; z stored bf16 ==========
__global__ __launch_bounds__(256) void k_gemm(const unsigned short* __restrict__ xh,
                                              const unsigned short* __restrict__ cbt,
                                              const unsigned short* __restrict__ Wb, const float* __restrict__ b,
                                              unsigned short* __restrict__ zb16, float* __restrict__ colsums, int Ntiles){
  __shared__ float rowss[2][16][4];
  const int tid = threadIdx.x;
  const int w = tid >> 6, l = tid & 63;
  const int l15 = l & 15, lhi = l >> 4;
  const int cb = w * 32;
  short8 bf[2][8];
  #pragma unroll
  for (int t=0;t<2;t++){
    #pragma unroll
    for (int s=0;s<8;s++)
      bf[t][s] = *(const short8*)(Wb + (size_t)(cb + t*16 + l15)*TWO_HID + s*32 + lhi*8);
  }
  const float bias0 = b[cb + l15];
  const float bias1 = b[cb + 16 + l15];
  float s1a = 0.f, s2a = 0.f, s1b = 0.f, s2b = 0.f;
  int pp = 0;
  for (int tile = blockIdx.x; tile < Ntiles; tile += gridDim.x, pp ^= 1){
    const int row0 = tile * 16;
    f32x4 acc0 = {0.f,0.f,0.f,0.f}, acc1 = {0.f,0.f,0.f,0.f};
    #pragma unroll
    for (int s=0;s<4;s++){
      short8 a = *(const short8*)(xh + (size_t)(row0 + l15)*HID + s*32 + lhi*8);
      acc0 = __builtin_amdgcn_mfma_f32_16x16x32_bf16(a, bf[0][s], acc0, 0,0,0);
      acc1 = __builtin_amdgcn_mfma_f32_16x16x32_bf16(a, bf[1][s], acc1, 0,0,0);
    }
    #pragma unroll
    for (int s=0;s<4;s++){
      short8 a = *(const short8*)(cbt + (size_t)(row0 + l15)*HID + s*32 + lhi*8);
      acc0 = __builtin_amdgcn_mfma_f32_16x16x32_bf16(a, bf[0][4+s], acc0, 0,0,0);
      acc1 = __builtin_amdgcn_mfma_f32_16x16x32_bf16(a, bf[1][4+s], acc1, 0,0,0);
    }
    float v0[4], v1[4], pr[4];
    #pragma unroll
    for (int r=0;r<4;r++){
      v0[r] = acc0[r] + bias0;
      v1[r] = acc1[r] + bias1;
      pr[r] = v0[r]*v0[r] + v1[r]*v1[r];
    }
    #pragma unroll
    for (int m=1;m<=8;m<<=1){
      #pragma unroll
      for (int r=0;r<4;r++) pr[r] += __shfl_xor(pr[r], m, 64);
    }
    if (l15 == 0){
      #pragma unroll
      for (int r=0;r<4;r++) rowss[pp][lhi*4+r][w] = pr[r];
    }
    __syncthreads();
    #pragma unroll
    for (int r=0;r<4;r++){
      const int i = lhi*4 + r;
      f32x4 q = *(const f32x4*)&rowss[pp][i][0];
      float ss = (q[0]+q[1]) + (q[2]+q[3]);
      float sc = 1.f / fmaxf(sqrtf(ss), 1e-12f);
      float z0 = fmaxf(v0[r]*sc, 0.f);
      float z1 = fmaxf(v1[r]*sc, 0.f);
      zb16[(size_t)(row0+i)*HID + cb + l15]      = f2b(z0);
      zb16[(size_t)(row0+i)*HID + cb + 16 + l15] = f2b(z1);
      s1a += z0; s2a += z0*z0;
      s1b += z1; s2b += z1*z1;
    }
  }
  s1a += __shfl_xor(s1a,16,64); s1a += __shfl_xor(s1a,32,64);
  s2a += __shfl_xor(s2a,16,64); s2a += __shfl_xor(s2a,32,64);
  s1b += __shfl_xor(s1b,16,64); s1b += __shfl_xor(s1b,32,64);
  s2b += __shfl_xor(s2b,16,64); s2b += __shfl_xor(s2b,32,64);
  if (lhi == 0){
    atomicAdd(&colsums[cb + l15],            s1a);
    atomicAdd(&colsums[128 + cb + l15],      s2a);
    atomicAdd(&colsums[cb + 16 + l15],       s1b);
    atomicAdd(&colsums[128 + cb + 16 + l15], s2b);
  }
}

// ====== fused BN-apply(prev layer) + incremental aggregation for this layer ======
// per node v (1 wave):  h += zbn[v];  xh = bf16(h);  c += mean_nbrs(z)*sc + sh*[deg>0]
__global__ __launch_bounds__(256) void k_aggbn(const unsigned* __restrict__ zbu,
                                               const float* __restrict__ colsums,
                                               const float* __restrict__ gamma, const float* __restrict__ beta,
                                               float* __restrict__ h, unsigned* __restrict__ xhu,
                                               unsigned* __restrict__ cbu,
                                               const int* __restrict__ offs, const int* __restrict__ ssrc,
                                               const float* __restrict__ invd, int N, float invN){
  int gid = blockIdx.x*blockDim.x + threadIdx.x;
  int node = gid >> 6;
  int lane = gid & 63;
  if (node >= N) return;
  // BN affine for this lane's column pair
  float2 s1 = ((const float2*)colsums)[lane];
  float2 s2 = ((const float2*)(colsums + 128))[lane];
  float2 g  = ((const float2*)gamma)[lane];
  float2 bt = ((const float2*)beta)[lane];
  float mux = s1.x*invN,           muy = s1.y*invN;
  float vax = s2.x*invN - mux*mux, vay = s2.y*invN - muy*muy;
  float scx = g.x * rsqrtf(vax + 1e-5f), scy = g.y * rsqrtf(vay + 1e-5f);
  float shx = bt.x - mux*scx,            shy = bt.y - muy*scy;

  // BN apply + residual for own node
  size_t idx = (size_t)node*64 + lane;
  unsigned zu = zbu[idx];
  float2 hv = ((const float2*)h)[idx];
  float nx = fmaf(blo(zu), scx, hv.x + shx);
  float ny = fmaf(bhi(zu), scy, hv.y + shy);
  ((float2*)h)[idx] = make_float2(nx, ny);
  xhu[idx] = pack2(nx, ny);

  // incremental aggregate: gather z of neighbors
  int e0 = offs[node], e1 = offs[node+1];
  float ax = 0.f, ay = 0.f;
  int e = e0;
  for (; e + 7 < e1; e += 8){
    int a0=ssrc[e],a1=ssrc[e+1],a2=ssrc[e+2],a3=ssrc[e+3];
    int a4=ssrc[e+4],a5=ssrc[e+5],a6=ssrc[e+6],a7=ssrc[e+7];
    unsigned u0=zbu[(size_t)a0*64+lane], u1=zbu[(size_t)a1*64+lane];
    unsigned u2=zbu[(size_t)a2*64+lane], u3=zbu[(size_t)a3*64+lane];
    unsigned u4=zbu[(size_t)a4*64+lane], u5=zbu[(size_t)a5*64+lane];
    unsigned u6=zbu[(size_t)a6*64+lane], u7=zbu[(size_t)a7*64+lane];
    ax += ((blo(u0)+blo(u1))+(blo(u2)+blo(u3))) + ((blo(u4)+blo(u5))+(blo(u6)+blo(u7)));
    ay += ((bhi(u0)+bhi(u1))+(bhi(u2)+bhi(u3))) + ((bhi(u4)+bhi(u5))+(bhi(u6)+bhi(u7)));
  }
  for (; e + 1 < e1; e += 2){
    unsigned u0 = zbu[(size_t)ssrc[e]*64 + lane];
    unsigned u1 = zbu[(size_t)ssrc[e+1]*64 + lane];
    ax += blo(u0) + blo(u1);
    ay += bhi(u0) + bhi(u1);
  }
  if (e < e1){
    unsigned u0 = zbu[(size_t)ssrc[e]*64 + lane];
    ax += blo(u0); ay += bhi(u0);
  }
  float idv = invd[node];
  float ida = fabsf(idv);
  float m = (idv > 0.f) ? 1.f : 0.f;
  unsigned cu = cbu[idx];
  float cx = blo(cu) + fmaf(ax*ida, scx, shx)*m;
  float cy = bhi(cu) + fmaf(ay*ida, scy, shy)*m;
  cbu[idx] = pack2(cx, cy);
}

// ================= final BN apply (layer 4): h += zbn; no mirror needed =================
__global__ __launch_bounds__(256) void k_bnfinal(const unsigned* __restrict__ zbu,
                                                 const float* __restrict__ colsums,
                                                 const float* __restrict__ gamma, const float* __restrict__ beta,
                                                 float* __restrict__ h, int Nh, float invN){
  int i = blockIdx.x*blockDim.x + threadIdx.x;
  if (i >= Nh) return;
  int j = i & 63;
  float2 s1 = ((const float2*)colsums)[j];
  float2 s2 = ((const float2*)(colsums + 128))[j];
  float2 g  = ((const float2*)gamma)[j];
  float2 bt = ((const float2*)beta)[j];
  float mux = s1.x*invN,           muy = s1.y*invN;
  float vax = s2.x*invN - mux*mux, vay = s2.y*invN - muy*muy;
  float scx = g.x * rsqrtf(vax + 1e-5f), scy = g.y * rsqrtf(vay + 1e-5f);
  float shx = bt.x - mux*scx,            shy = bt.y - muy*scy;
  unsigned zu = zbu[i];
  float2 hv = ((const float2*)h)[i];
  float nx = fmaf(blo(zu), scx, hv.x + shx);
  float ny = fmaf(bhi(zu), scy, hv.y + shy);
  ((float2*)h)[i] = make_float2(nx, ny);
}

extern "C" void kernel_launch(void* const* d_in, const int* in_sizes, int n_in,
                              void* d_out, int out_size, void* d_ws, size_t ws_size,
                              hipStream_t stream){
  const float* h0   = (const float*)d_in[0];
  const int*   src  = (const int*)d_in[1];
  const int*   dst  = (const int*)d_in[2];
  const float* Wemb = (const float*)d_in[3];
  const float* bemb = (const float*)d_in[4];
  const float* Ws   = (const float*)d_in[5];
  const float* bs   = (const float*)d_in[6];
  const float* gam  = (const float*)d_in[7];
  const float* bet  = (const float*)d_in[8];
  const int N = in_sizes[0] / HID;
  const int E = in_sizes[1];
  const int Ntiles = N / 16;
  const int NB = (N + 255) / 256;
  float* h = (float*)d_out;

  char* ws = (char*)d_ws;
  size_t off = 0;
  auto alloc = [&](size_t bytes)->char*{
    char* p = ws + off;
    off = (off + bytes + 255) & ~(size_t)255;
    return p;
  };
  int*   deg      = (int*)  alloc((size_t)N*4);        // deg,cursor,colsums contiguous -> one memset
  int*   cursor   = (int*)  alloc((size_t)N*4);
  float* colsums  = (float*)alloc(4*256*4);
  int*   offs     = (int*)  alloc((size_t)(N+1)*4);
  int*   loc      = (int*)  alloc((size_t)N*4);
  int*   bsum     = (int*)  alloc((size_t)NB*4);
  float* invd     = (float*)alloc((size_t)N*4);
  int*   ssrc     = (int*)  alloc((size_t)E*4);
  unsigned short* Wembb = (unsigned short*)alloc((size_t)NEMB*2);
  unsigned short* Wsb   = (unsigned short*)alloc((size_t)NWS*2);
  unsigned short* xh    = (unsigned short*)alloc((size_t)N*HID*2);   // bf16 h mirror
  unsigned short* cbt   = (unsigned short*)alloc((size_t)N*HID*2);   // bf16 aggregate (incremental)
  unsigned short* zb16  = (unsigned short*)alloc((size_t)N*HID*2);   // bf16 z

  hipMemsetAsync(deg, 0, (size_t)2*N*4 + 4*256*4, stream);

  CsrParams cp;
  cp.src = src; cp.dst = dst; cp.Wemb = Wemb; cp.Ws = Ws;
  cp.Wembb = Wembb; cp.Wsb = Wsb;
  cp.deg = deg; cp.cursor = cursor; cp.offs = offs; cp.loc = loc; cp.bsum = bsum;
  cp.invd = invd; cp.ssrc = ssrc;
  cp.N = N; cp.E = E; cp.NB = NB;
  void* args[] = { &cp };
  hipError_t cerr = hipLaunchCooperativeKernel((const void*)k_csr, dim3(1024), dim3(256),
                                               args, 0, stream);
  if (cerr != hipSuccess){
    hipLaunchKernelGGL(k_wcvt,  dim3((NEMB+NWS+255)/256), dim3(256), 0, stream, Wemb, Ws, Wembb, Wsb, NEMB, NWS);
    hipLaunchKernelGGL(k_deg,   dim3((E+255)/256),   dim3(256), 0, stream, dst, deg, E);
    hipLaunchKernelGGL(k_scan1, dim3(NB),  dim3(256), 0, stream, deg, loc, bsum, N);
    hipLaunchKernelGGL(k_scan2, dim3(1),   dim3(256), 0, stream, bsum, NB);
    hipLaunchKernelGGL(k_scan3, dim3(NB),  dim3(256), 0, stream, deg, loc, bsum, offs, invd, N, E);
    hipLaunchKernelGGL(k_fill,  dim3((E+255)/256),   dim3(256), 0, stream, src, dst, offs, cursor, ssrc, E);
  }

  hipLaunchKernelGGL(k_embed, dim3(512), dim3(256), 0, stream, h0, Wembb, bemb, h, xh, Ntiles);

  const float invN = 1.0f / (float)N;
  const int aggGrid = (N*64 + 255) / 256;

  // layer 1
  hipLaunchKernelGGL(k_agg, dim3(aggGrid), dim3(256), 0, stream,
                     (const unsigned*)xh, offs, ssrc, invd, (unsigned*)cbt, N);
  hipLaunchKernelGGL(k_gemm, dim3(512), dim3(256), 0, stream,
                     xh, cbt, Wsb, bs, zb16, colsums, Ntiles);
  // layers 2..4
  for (int l=1;l<4;l++){
    hipLaunchKernelGGL(k_aggbn, dim3(aggGrid), dim3(256), 0, stream,
                       (const unsigned*)zb16, colsums + (size_t)(l-1)*256,
                       gam + (size_t)(l-1)*HID, bet + (size_t)(l-1)*HID,
                       h, (unsigned*)xh, (unsigned*)cbt, offs, ssrc, invd, N, invN);
    hipLaunchKernelGGL(k_gemm, dim3(512), dim3(256), 0, stream,
                       xh, cbt, Wsb + (size_t)l*HID*TWO_HID, bs + (size_t)l*HID,
                       zb16, colsums + (size_t)l*256, Ntiles);
  }
  // final BN (layer 4)
  hipLaunchKernelGGL(k_bnfinal, dim3(aggGrid), dim3(256), 0, stream,
                     (const unsigned*)zb16, colsums + (size_t)3*256,
                     gam + (size_t)3*HID, bet + (size_t)3*HID, h, N*64, invN);
}

// Round 9
// 417.137 us; speedup vs baseline: 6.1099x; 2.0806x over previous
//
#include <hip/hip_runtime.h>

#define HID 128
#define TWO_HID 256
#define NEMB (HID*HID)
#define NWS  (4*HID*TWO_HID)

typedef __attribute__((ext_vector_type(8))) short short8;
typedef __attribute__((ext_vector_type(4))) float f32x4;

__device__ inline unsigned short f2b(float f){
  unsigned u = __float_as_uint(f);
  unsigned r = u + 0x7FFFu + ((u >> 16) & 1u);   // RNE
  return (unsigned short)(r >> 16);
}
__device__ inline unsigned pack2(float lo, float hi){
  return (unsigned)f2b(lo) | ((unsigned)f2b(hi) << 16);
}
__device__ inline float blo(unsigned u){ return __uint_as_float(u << 16); }
__device__ inline float bhi(unsigned u){ return __uint_as_float(u & 0xFFFF0000u); }

// ---------- CSR build (regular launches; NO cooperative sync: grid.sync ~100us on MI355X) ----------
__global__ void k_deg(const int* __restrict__ dst, int* __restrict__ deg, int E){
  int e = blockIdx.x*blockDim.x + threadIdx.x;
  if (e < E) atomicAdd(&deg[dst[e]], 1);
}

__global__ __launch_bounds__(256) void k_scan1(const int* __restrict__ deg, int* __restrict__ loc,
                                               int* __restrict__ bsum, int N){
  const int tid = threadIdx.x;
  const int i = blockIdx.x*256 + tid;
  const int lane = tid & 63, wv = tid >> 6;
  int v = (i < N) ? deg[i] : 0;
  int s = v;
  #pragma unroll
  for (int m=1; m<64; m<<=1){
    int t = __shfl_up(s, m, 64);
    if (lane >= m) s += t;
  }
  __shared__ int wsum[4];
  if (lane == 63) wsum[wv] = s;
  __syncthreads();
  if (tid == 0){
    int a = 0;
    #pragma unroll
    for (int q=0;q<4;q++){ int t = wsum[q]; wsum[q] = a; a += t; }
    bsum[blockIdx.x] = a;
  }
  __syncthreads();
  if (i < N) loc[i] = s - v + wsum[wv];
}

__global__ __launch_bounds__(256) void k_scan2(int* __restrict__ bsum, int nb){
  const int tid = threadIdx.x;
  const int lane = tid & 63, wv = tid >> 6;
  int v = (tid < nb) ? bsum[tid] : 0;
  int s = v;
  #pragma unroll
  for (int m=1; m<64; m<<=1){
    int t = __shfl_up(s, m, 64);
    if (lane >= m) s += t;
  }
  __shared__ int wsum[4];
  if (lane == 63) wsum[wv] = s;
  __syncthreads();
  if (tid == 0){
    int a = 0;
    #pragma unroll
    for (int q=0;q<4;q++){ int t = wsum[q]; wsum[q] = a; a += t; }
  }
  __syncthreads();
  if (tid < nb) bsum[tid] = s - v + wsum[wv];
}

__global__ __launch_bounds__(256) void k_scan3(const int* __restrict__ deg, const int* __restrict__ loc,
                                               const int* __restrict__ bsum, int* __restrict__ offs,
                                               float* __restrict__ invd, int N, int E){
  const int i = blockIdx.x*256 + threadIdx.x;
  if (i < N){
    offs[i] = loc[i] + bsum[blockIdx.x];
    int d = deg[i];
    invd[i] = (d > 0) ? 1.0f / (float)d : -1.0f;   // deg0 sentinel
  }
  if (i == 0) offs[N] = E;
}

__global__ void k_fill(const int* __restrict__ src, const int* __restrict__ dst,
                       const int* __restrict__ offs, int* __restrict__ cursor,
                       int* __restrict__ ssrc, int E){
  int e = blockIdx.x*blockDim.x + threadIdx.x;
  if (e < E){
    int d = dst[e];
    int pos = offs[d] + atomicAdd(&cursor[d], 1);
    ssrc[pos] = src[e];
  }
}

__global__ void k_wcvt(const float* __restrict__ Wemb, const float* __restrict__ Ws,
                       unsigned short* __restrict__ Wembb, unsigned short* __restrict__ Wsb,
                       int nEmb, int nWs){
  int i = blockIdx.x*blockDim.x + threadIdx.x;
  if (i < nEmb) Wembb[i] = f2b(Wemb[i]);
  else if (i < nEmb + nWs) Wsb[i - nEmb] = f2b(Ws[i - nEmb]);
}

// ---------- input embedding (MFMA bf16) ----------
__global__ __launch_bounds__(256) void k_embed(const float* __restrict__ h0, const unsigned short* __restrict__ Wb,
                                               const float* __restrict__ b, float* __restrict__ h,
                                               unsigned short* __restrict__ xh, int Ntiles){
  const int tid = threadIdx.x;
  const int w = tid >> 6, l = tid & 63;
  const int l15 = l & 15, lhi = l >> 4;
  const int cb = w * 32;
  short8 bf[2][4];
  #pragma unroll
  for (int t=0;t<2;t++){
    #pragma unroll
    for (int s=0;s<4;s++)
      bf[t][s] = *(const short8*)(Wb + (size_t)(cb + t*16 + l15)*HID + s*32 + lhi*8);
  }
  const float bias0 = b[cb + l15];
  const float bias1 = b[cb + 16 + l15];
  for (int tile = blockIdx.x; tile < Ntiles; tile += gridDim.x){
    const int row0 = tile * 16;
    f32x4 acc0 = {0.f,0.f,0.f,0.f}, acc1 = {0.f,0.f,0.f,0.f};
    #pragma unroll
    for (int s=0;s<4;s++){
      const float* ap = h0 + (size_t)(row0 + l15)*HID + s*32 + lhi*8;
      float4 x0 = *(const float4*)ap;
      float4 x1 = *(const float4*)(ap + 4);
      short8 f;
      f[0]=(short)f2b(x0.x); f[1]=(short)f2b(x0.y); f[2]=(short)f2b(x0.z); f[3]=(short)f2b(x0.w);
      f[4]=(short)f2b(x1.x); f[5]=(short)f2b(x1.y); f[6]=(short)f2b(x1.z); f[7]=(short)f2b(x1.w);
      acc0 = __builtin_amdgcn_mfma_f32_16x16x32_bf16(f, bf[0][s], acc0, 0,0,0);
      acc1 = __builtin_amdgcn_mfma_f32_16x16x32_bf16(f, bf[1][s], acc1, 0,0,0);
    }
    #pragma unroll
    for (int r=0;r<4;r++){
      const int row = row0 + lhi*4 + r;
      float v0 = acc0[r] + bias0;
      float v1 = acc1[r] + bias1;
      h[(size_t)row*HID + cb + l15]      = v0;
      h[(size_t)row*HID + cb + 16 + l15] = v1;
      xh[(size_t)row*HID + cb + l15]      = f2b(v0);
      xh[(size_t)row*HID + cb + 16 + l15] = f2b(v1);
    }
  }
}

// ---------- layer-1 aggregation: cbt[v] = mean of xh[nbrs] ----------
__global__ __launch_bounds__(256) void k_agg(const unsigned* __restrict__ xhu, const int* __restrict__ offs,
                                             const int* __restrict__ ssrc, const float* __restrict__ invd,
                                             unsigned* __restrict__ cbu, int N){
  int gid = blockIdx.x*blockDim.x + threadIdx.x;
  int node = gid >> 6;
  int lane = gid & 63;
  if (node >= N) return;
  int e0 = offs[node], e1 = offs[node+1];
  float ax = 0.f, ay = 0.f;
  int e = e0;
  for (; e + 7 < e1; e += 8){
    int a0=ssrc[e],a1=ssrc[e+1],a2=ssrc[e+2],a3=ssrc[e+3];
    int a4=ssrc[e+4],a5=ssrc[e+5],a6=ssrc[e+6],a7=ssrc[e+7];
    unsigned u0=xhu[(size_t)a0*64+lane], u1=xhu[(size_t)a1*64+lane];
    unsigned u2=xhu[(size_t)a2*64+lane], u3=xhu[(size_t)a3*64+lane];
    unsigned u4=xhu[(size_t)a4*64+lane], u5=xhu[(size_t)a5*64+lane];
    unsigned u6=xhu[(size_t)a6*64+lane], u7=xhu[(size_t)a7*64+lane];
    ax += ((blo(u0)+blo(u1))+(blo(u2)+blo(u3))) + ((blo(u4)+blo(u5))+(blo(u6)+blo(u7)));
    ay += ((bhi(u0)+bhi(u1))+(bhi(u2)+bhi(u3))) + ((bhi(u4)+bhi(u5))+(bhi(u6)+bhi(u7)));
  }
  for (; e + 1 < e1; e += 2){
    unsigned u0 = xhu[(size_t)ssrc[e]*64 + lane];
    unsigned u1 = xhu[(size_t)ssrc[e+1]*64 + lane];
    ax += blo(u0) + blo(u1);
    ay += bhi(u0) + bhi(u1);
  }
  if (e < e1){
    unsigned u0 = xhu[(size_t)ssrc[e]*64 + lane];
    ax += blo(u0); ay += bhi(u0);
  }
  float id = invd[node];
  float ida = fabsf(id);
  float m = (id > 0.f) ? 1.f : 0.f;
  cbu[(size_t)node*64 + lane] = pack2(ax*ida*m, ay*ida*m);
}

// ---------- layer GEMM (MFMA bf16) + L2norm + relu + BN partials; z stored bf16 ----------
__global__ __launch_bounds__(256) void k_gemm(const unsigned short* __restrict__ xh,
                                              const unsigned short* __restrict__ cbt,
                                              const unsigned short* __restrict__ Wb, const float* __restrict__ b,
                                              unsigned short* __restrict__ zb16, float* __restrict__ colsums, int Ntiles){
  __shared__ float rowss[2][16][4];
  const int tid = threadIdx.x;
  const int w = tid >> 6, l = tid & 63;
  const int l15 = l & 15, lhi = l >> 4;
  const int cb = w * 32;
  short8 bf[2][8];
  #pragma unroll
  for (int t=0;t<2;t++){
    #pragma unroll
    for (int s=0;s<8;s++)
      bf[t][s] = *(const short8*)(Wb + (size_t)(cb + t*16 + l15)*TWO_HID + s*32 + lhi*8);
  }
  const float bias0 = b[cb + l15];
  const float bias1 = b[cb + 16 + l15];
  float s1a = 0.f, s2a = 0.f, s1b = 0.f, s2b = 0.f;
  int pp = 0;
  for (int tile = blockIdx.x; tile < Ntiles; tile += gridDim.x, pp ^= 1){
    const int row0 = tile * 16;
    f32x4 acc0 = {0.f,0.f,0.f,0.f}, acc1 = {0.f,0.f,0.f,0.f};
    #pragma unroll
    for (int s=0;s<4;s++){
      short8 a = *(const short8*)(xh + (size_t)(row0 + l15)*HID + s*32 + lhi*8);
      acc0 = __builtin_amdgcn_mfma_f32_16x16x32_bf16(a, bf[0][s], acc0, 0,0,0);
      acc1 = __builtin_amdgcn_mfma_f32_16x16x32_bf16(a, bf[1][s], acc1, 0,0,0);
    }
    #pragma unroll
    for (int s=0;s<4;s++){
      short8 a = *(const short8*)(cbt + (size_t)(row0 + l15)*HID + s*32 + lhi*8);
      acc0 = __builtin_amdgcn_mfma_f32_16x16x32_bf16(a, bf[0][4+s], acc0, 0,0,0);
      acc1 = __builtin_amdgcn_mfma_f32_16x16x32_bf16(a, bf[1][4+s], acc1, 0,0,0);
    }
    float v0[4], v1[4], pr[4];
    #pragma unroll
    for (int r=0;r<4;r++){
      v0[r] = acc0[r] + bias0;
      v1[r] = acc1[r] + bias1;
      pr[r] = v0[r]*v0[r] + v1[r]*v1[r];
    }
    #pragma unroll
    for (int m=1;m<=8;m<<=1){
      #pragma unroll
      for (int r=0;r<4;r++) pr[r] += __shfl_xor(pr[r], m, 64);
    }
    if (l15 == 0){
      #pragma unroll
      for (int r=0;r<4;r++) rowss[pp][lhi*4+r][w] = pr[r];
    }
    __syncthreads();
    #pragma unroll
    for (int r=0;r<4;r++){
      const int i = lhi*4 + r;
      f32x4 q = *(const f32x4*)&rowss[pp][i][0];
      float ss = (q[0]+q[1]) + (q[2]+q[3]);
      float sc = 1.f / fmaxf(sqrtf(ss), 1e-12f);
      float z0 = fmaxf(v0[r]*sc, 0.f);
      float z1 = fmaxf(v1[r]*sc, 0.f);
      zb16[(size_t)(row0+i)*HID + cb + l15]      = f2b(z0);
      zb16[(size_t)(row0+i)*HID + cb + 16 + l15] = f2b(z1);
      s1a += z0; s2a += z0*z0;
      s1b += z1; s2b += z1*z1;
    }
  }
  s1a += __shfl_xor(s1a,16,64); s1a += __shfl_xor(s1a,32,64);
  s2a += __shfl_xor(s2a,16,64); s2a += __shfl_xor(s2a,32,64);
  s1b += __shfl_xor(s1b,16,64); s1b += __shfl_xor(s1b,32,64);
  s2b += __shfl_xor(s2b,16,64); s2b += __shfl_xor(s2b,32,64);
  if (lhi == 0){
    atomicAdd(&colsums[cb + l15],            s1a);
    atomicAdd(&colsums[128 + cb + l15],      s2a);
    atomicAdd(&colsums[cb + 16 + l15],       s1b);
    atomicAdd(&colsums[128 + cb + 16 + l15], s2b);
  }
}

// ====== fused BN-apply(prev layer) + incremental aggregation for next layer ======
// per node v (1 wave):  h += bn(z[v]);  xh = bf16(h);  c += mean_nbrs(z)*sc + sh*[deg>0]
__global__ __launch_bounds__(256) void k_aggbn(const unsigned* __restrict__ zbu,
                                               const float* __restrict__ colsums,
                                               const float* __restrict__ gamma, const float* __restrict__ beta,
                                               float* __restrict__ h, unsigned* __restrict__ xhu,
                                               unsigned* __restrict__ cbu,
                                               const int* __restrict__ offs, const int* __restrict__ ssrc,
                                               const float* __restrict__ invd, int N, float invN){
  int gid = blockIdx.x*blockDim.x + threadIdx.x;
  int node = gid >> 6;
  int lane = gid & 63;
  if (node >= N) return;
  float2 s1 = ((const float2*)colsums)[lane];
  float2 s2 = ((const float2*)(colsums + 128))[lane];
  float2 g  = ((const float2*)gamma)[lane];
  float2 bt = ((const float2*)beta)[lane];
  float mux = s1.x*invN,           muy = s1.y*invN;
  float vax = s2.x*invN - mux*mux, vay = s2.y*invN - muy*muy;
  float scx = g.x * rsqrtf(vax + 1e-5f), scy = g.y * rsqrtf(vay + 1e-5f);
  float shx = bt.x - mux*scx,            shy = bt.y - muy*scy;

  size_t idx = (size_t)node*64 + lane;
  unsigned zu = zbu[idx];
  float2 hv = ((const float2*)h)[idx];
  float nx = fmaf(blo(zu), scx, hv.x + shx);
  float ny = fmaf(bhi(zu), scy, hv.y + shy);
  ((float2*)h)[idx] = make_float2(nx, ny);
  xhu[idx] = pack2(nx, ny);

  int e0 = offs[node], e1 = offs[node+1];
  float ax = 0.f, ay = 0.f;
  int e = e0;
  for (; e + 7 < e1; e += 8){
    int a0=ssrc[e],a1=ssrc[e+1],a2=ssrc[e+2],a3=ssrc[e+3];
    int a4=ssrc[e+4],a5=ssrc[e+5],a6=ssrc[e+6],a7=ssrc[e+7];
    unsigned u0=zbu[(size_t)a0*64+lane], u1=zbu[(size_t)a1*64+lane];
    unsigned u2=zbu[(size_t)a2*64+lane], u3=zbu[(size_t)a3*64+lane];
    unsigned u4=zbu[(size_t)a4*64+lane], u5=zbu[(size_t)a5*64+lane];
    unsigned u6=zbu[(size_t)a6*64+lane], u7=zbu[(size_t)a7*64+lane];
    ax += ((blo(u0)+blo(u1))+(blo(u2)+blo(u3))) + ((blo(u4)+blo(u5))+(blo(u6)+blo(u7)));
    ay += ((bhi(u0)+bhi(u1))+(bhi(u2)+bhi(u3))) + ((bhi(u4)+bhi(u5))+(bhi(u6)+bhi(u7)));
  }
  for (; e + 1 < e1; e += 2){
    unsigned u0 = zbu[(size_t)ssrc[e]*64 + lane];
    unsigned u1 = zbu[(size_t)ssrc[e+1]*64 + lane];
    ax += blo(u0) + blo(u1);
    ay += bhi(u0) + bhi(u1);
  }
  if (e < e1){
    unsigned u0 = zbu[(size_t)ssrc[e]*64 + lane];
    ax += blo(u0); ay += bhi(u0);
  }
  float idv = invd[node];
  float ida = fabsf(idv);
  float m = (idv > 0.f) ? 1.f : 0.f;
  unsigned cu = cbu[idx];
  float cx = blo(cu) + fmaf(ax*ida, scx, shx)*m;
  float cy = bhi(cu) + fmaf(ay*ida, scy, shy)*m;
  cbu[idx] = pack2(cx, cy);
}

// ---------- final BN apply (layer 4) ----------
__global__ __launch_bounds__(256) void k_bnfinal(const unsigned* __restrict__ zbu,
                                                 const float* __restrict__ colsums,
                                                 const float* __restrict__ gamma, const float* __restrict__ beta,
                                                 float* __restrict__ h, int Nh, float invN){
  int i = blockIdx.x*blockDim.x + threadIdx.x;
  if (i >= Nh) return;
  int j = i & 63;
  float2 s1 = ((const float2*)colsums)[j];
  float2 s2 = ((const float2*)(colsums + 128))[j];
  float2 g  = ((const float2*)gamma)[j];
  float2 bt = ((const float2*)beta)[j];
  float mux = s1.x*invN,           muy = s1.y*invN;
  float vax = s2.x*invN - mux*mux, vay = s2.y*invN - muy*muy;
  float scx = g.x * rsqrtf(vax + 1e-5f), scy = g.y * rsqrtf(vay + 1e-5f);
  float shx = bt.x - mux*scx,            shy = bt.y - muy*scy;
  unsigned zu = zbu[i];
  float2 hv = ((const float2*)h)[i];
  float nx = fmaf(blo(zu), scx, hv.x + shx);
  float ny = fmaf(bhi(zu), scy, hv.y + shy);
  ((float2*)h)[i] = make_float2(nx, ny);
}

extern "C" void kernel_launch(void* const* d_in, const int* in_sizes, int n_in,
                              void* d_out, int out_size, void* d_ws, size_t ws_size,
                              hipStream_t stream){
  const float* h0   = (const float*)d_in[0];
  const int*   src  = (const int*)d_in[1];
  const int*   dst  = (const int*)d_in[2];
  const float* Wemb = (const float*)d_in[3];
  const float* bemb = (const float*)d_in[4];
  const float* Ws   = (const float*)d_in[5];
  const float* bs   = (const float*)d_in[6];
  const float* gam  = (const float*)d_in[7];
  const float* bet  = (const float*)d_in[8];
  const int N = in_sizes[0] / HID;
  const int E = in_sizes[1];
  const int Ntiles = N / 16;
  const int NB = (N + 255) / 256;
  float* h = (float*)d_out;

  char* ws = (char*)d_ws;
  size_t off = 0;
  auto alloc = [&](size_t bytes)->char*{
    char* p = ws + off;
    off = (off + bytes + 255) & ~(size_t)255;
    return p;
  };
  int*   deg      = (int*)  alloc((size_t)N*4);        // deg,cursor,colsums contiguous -> one memset
  int*   cursor   = (int*)  alloc((size_t)N*4);
  float* colsums  = (float*)alloc(4*256*4);
  int*   offs     = (int*)  alloc((size_t)(N+1)*4);
  int*   loc      = (int*)  alloc((size_t)N*4);
  int*   bsum     = (int*)  alloc((size_t)NB*4);
  float* invd     = (float*)alloc((size_t)N*4);
  int*   ssrc     = (int*)  alloc((size_t)E*4);
  unsigned short* Wembb = (unsigned short*)alloc((size_t)NEMB*2);
  unsigned short* Wsb   = (unsigned short*)alloc((size_t)NWS*2);
  unsigned short* xh    = (unsigned short*)alloc((size_t)N*HID*2);   // bf16 h mirror
  unsigned short* cbt   = (unsigned short*)alloc((size_t)N*HID*2);   // bf16 aggregate (incremental)
  unsigned short* zb16  = (unsigned short*)alloc((size_t)N*HID*2);   // bf16 z

  hipMemsetAsync(deg, 0, (size_t)2*N*4 + 4*256*4, stream);

  hipLaunchKernelGGL(k_wcvt,  dim3((NEMB+NWS+255)/256), dim3(256), 0, stream, Wemb, Ws, Wembb, Wsb, NEMB, NWS);
  hipLaunchKernelGGL(k_deg,   dim3((E+255)/256),   dim3(256), 0, stream, dst, deg, E);
  hipLaunchKernelGGL(k_scan1, dim3(NB),  dim3(256), 0, stream, deg, loc, bsum, N);
  hipLaunchKernelGGL(k_scan2, dim3(1),   dim3(256), 0, stream, bsum, NB);
  hipLaunchKernelGGL(k_scan3, dim3(NB),  dim3(256), 0, stream, deg, loc, bsum, offs, invd, N, E);
  hipLaunchKernelGGL(k_fill,  dim3((E+255)/256),   dim3(256), 0, stream, src, dst, offs, cursor, ssrc, E);

  hipLaunchKernelGGL(k_embed, dim3(512), dim3(256), 0, stream, h0, Wembb, bemb, h, xh, Ntiles);

  const float invN = 1.0f / (float)N;
  const int aggGrid = (N*64 + 255) / 256;

  // layer 1
  hipLaunchKernelGGL(k_agg, dim3(aggGrid), dim3(256), 0, stream,
                     (const unsigned*)xh, offs, ssrc, invd, (unsigned*)cbt, N);
  hipLaunchKernelGGL(k_gemm, dim3(512), dim3(256), 0, stream,
                     xh, cbt, Wsb, bs, zb16, colsums, Ntiles);
  // layers 2..4
  for (int l=1;l<4;l++){
    hipLaunchKernelGGL(k_aggbn, dim3(aggGrid), dim3(256), 0, stream,
                       (const unsigned*)zb16, colsums + (size_t)(l-1)*256,
                       gam + (size_t)(l-1)*HID, bet + (size_t)(l-1)*HID,
                       h, (unsigned*)xh, (unsigned*)cbt, offs, ssrc, invd, N, invN);
    hipLaunchKernelGGL(k_gemm, dim3(512), dim3(256), 0, stream,
                       xh, cbt, Wsb + (size_t)l*HID*TWO_HID, bs + (size_t)l*HID,
                       zb16, colsums + (size_t)l*256, Ntiles);
  }
  // final BN (layer 4)
  hipLaunchKernelGGL(k_bnfinal, dim3(aggGrid), dim3(256), 0, stream,
                     (const unsigned*)zb16, colsums + (size_t)3*256,
                     gam + (size_t)3*HID, bet + (size_t)3*HID, h, N*64, invN);
}